// Round 3
// baseline (619.710 us; speedup 1.0000x reference)
//
#include <hip/hip_runtime.h>

#define N_NODES 20000
#define N_EDGES 320000
#define E_TOT   340000   // edges + self loops
#define N_GRAPHS 64
#define N_CLASSES 5
#define SLOPE 0.2f
#define EPS_BN 1e-5f

// ---------------- CSR build ----------------
__global__ void k_zero(int* __restrict__ p, int n) {
    int i = blockIdx.x * 256 + threadIdx.x;
    if (i < n) p[i] = 0;
}

__global__ void k_count(const int* __restrict__ ei, int* __restrict__ cnt) {
    int e = blockIdx.x * 256 + threadIdx.x;
    if (e >= E_TOT) return;
    int d = (e < N_EDGES) ? ei[N_EDGES + e] : (e - N_EDGES);
    atomicAdd(&cnt[d], 1);
}

__global__ __launch_bounds__(1024) void k_scan(const int* __restrict__ cnt,
                                               int* __restrict__ indptr,
                                               int* __restrict__ wptr) {
    __shared__ int smem[1024];
    const int t = threadIdx.x;
    const int per = (N_NODES + 1023) / 1024;  // 20
    const int i0 = t * per;
    int lsum = 0;
    for (int j = 0; j < per; ++j) {
        int i = i0 + j;
        if (i < N_NODES) lsum += cnt[i];
    }
    smem[t] = lsum;
    __syncthreads();
    for (int off = 1; off < 1024; off <<= 1) {
        int v = (t >= off) ? smem[t - off] : 0;
        __syncthreads();
        smem[t] += v;
        __syncthreads();
    }
    int run = smem[t] - lsum;  // exclusive prefix
    for (int j = 0; j < per; ++j) {
        int i = i0 + j;
        if (i < N_NODES) {
            indptr[i] = run;
            wptr[i] = run;
            run += cnt[i];
        }
    }
    if (t == 1023) indptr[N_NODES] = E_TOT;
}

__global__ void k_scatter(const int* __restrict__ ei, int* __restrict__ wptr,
                          int* __restrict__ esrc) {
    int e = blockIdx.x * 256 + threadIdx.x;
    if (e >= E_TOT) return;
    int s, d;
    if (e < N_EDGES) { s = ei[e]; d = ei[N_EDGES + e]; }
    else             { s = d = e - N_EDGES; }
    int pos = atomicAdd(&wptr[d], 1);
    esrc[pos] = s;
}

// ---------------- GEMM: C[MxN] = A[MxK] @ B[KxN], all f32 ----------------
__global__ __launch_bounds__(256) void k_gemm(const float* __restrict__ A,
                                              const float* __restrict__ B,
                                              float* __restrict__ C,
                                              int M, int K, int N) {
    __shared__ float As[16][68];  // [k][m]
    __shared__ float Bs[16][68];  // [k][n]
    const int tid = threadIdx.x;
    const int bm = blockIdx.x * 64;
    const int bn = blockIdx.y * 64;
    const int tx = tid & 15, ty = tid >> 4;
    const int ar = tid >> 2, akc = (tid & 3) * 4;
    const int br = tid >> 4, bbc = (tid & 15) * 4;
    const int gr = bm + ar;
    float acc[4][4] = {};
    for (int k0 = 0; k0 < K; k0 += 16) {
        float4 av4 = {0.f, 0.f, 0.f, 0.f};
        if (gr < M) av4 = *(const float4*)(A + (size_t)gr * K + k0 + akc);
        As[akc + 0][ar] = av4.x; As[akc + 1][ar] = av4.y;
        As[akc + 2][ar] = av4.z; As[akc + 3][ar] = av4.w;
        {
            const float4 bv4 = *(const float4*)(B + (size_t)(k0 + br) * N + bn + bbc);
            Bs[br][bbc + 0] = bv4.x; Bs[br][bbc + 1] = bv4.y;
            Bs[br][bbc + 2] = bv4.z; Bs[br][bbc + 3] = bv4.w;
        }
        __syncthreads();
#pragma unroll
        for (int kk = 0; kk < 16; ++kk) {
            const float4 av = *(const float4*)&As[kk][ty * 4];
            const float4 bv = *(const float4*)&Bs[kk][tx * 4];
            acc[0][0] += av.x * bv.x; acc[0][1] += av.x * bv.y; acc[0][2] += av.x * bv.z; acc[0][3] += av.x * bv.w;
            acc[1][0] += av.y * bv.x; acc[1][1] += av.y * bv.y; acc[1][2] += av.y * bv.z; acc[1][3] += av.y * bv.w;
            acc[2][0] += av.z * bv.x; acc[2][1] += av.z * bv.y; acc[2][2] += av.z * bv.z; acc[2][3] += av.z * bv.w;
            acc[3][0] += av.w * bv.x; acc[3][1] += av.w * bv.y; acc[3][2] += av.w * bv.z; acc[3][3] += av.w * bv.w;
        }
        __syncthreads();
    }
#pragma unroll
    for (int i = 0; i < 4; ++i) {
        int row = bm + ty * 4 + i;
        if (row < M) {
            float4 v;
            v.x = acc[i][0]; v.y = acc[i][1]; v.z = acc[i][2]; v.w = acc[i][3];
            *(float4*)(C + (size_t)row * N + bn + tx * 4) = v;
        }
    }
}

// ---------------- attention logits ----------------
template <int H>
__global__ __launch_bounds__(256) void k_al(const float* __restrict__ hin,
                                            const float* __restrict__ asrc,
                                            const float* __restrict__ adst,
                                            float* __restrict__ als, float* __restrict__ ald) {
    const int n = blockIdx.x * 4 + (threadIdx.x >> 6);
    const int lane = threadIdx.x & 63;
    if (H == 4) {
        const int c = lane * 4;  // == head*64 + part*4
        const float4 hv = *(const float4*)(hin + (size_t)n * 256 + c);
        const float4 sa = *(const float4*)(asrc + c);
        const float4 da = *(const float4*)(adst + c);
        float s = hv.x * sa.x + hv.y * sa.y + hv.z * sa.z + hv.w * sa.w;
        float d = hv.x * da.x + hv.y * da.y + hv.z * da.z + hv.w * da.w;
#pragma unroll
        for (int m = 1; m < 16; m <<= 1) {
            s += __shfl_xor(s, m, 64);
            d += __shfl_xor(d, m, 64);
        }
        if ((lane & 15) == 0) {
            const int head = lane >> 4;
            als[n * 4 + head] = s;
            ald[n * 4 + head] = d;
        }
    } else {
        const float hv = hin[(size_t)n * 64 + lane];
        float s = hv * asrc[lane];
        float d = hv * adst[lane];
#pragma unroll
        for (int m = 1; m < 64; m <<= 1) {
            s += __shfl_xor(s, m, 64);
            d += __shfl_xor(d, m, 64);
        }
        if (lane == 0) { als[n] = s; ald[n] = d; }
    }
}

// ---------------- fused GAT aggregate (+bias +BN +ReLU), 4 heads, 256 ch ----------------
__global__ __launch_bounds__(256) void k_agg4(const float* __restrict__ hin,
                                              const float* __restrict__ als,
                                              const float* __restrict__ ald,
                                              const int* __restrict__ indptr,
                                              const int* __restrict__ esrc,
                                              const float* __restrict__ bias,
                                              const float* __restrict__ gamma,
                                              const float* __restrict__ beta,
                                              const float* __restrict__ mean,
                                              const float* __restrict__ var,
                                              float* __restrict__ outp) {
    const int n = blockIdx.x * 4 + (threadIdx.x >> 6);
    const int lane = threadIdx.x & 63;
    const int beg = indptr[n], end = indptr[n + 1];
    // pass 1: per-head max over in-edges (16 lanes per head, lane%4 = head)
    const int h1 = lane & 3;
    const float aldn1 = ald[n * 4 + h1];
    float mx = -3.0e38f;
    for (int e = beg + (lane >> 2); e < end; e += 16) {
        const int s = esrc[e];
        float v = als[s * 4 + h1] + aldn1;
        v = (v > 0.f) ? v : SLOPE * v;
        mx = fmaxf(mx, v);
    }
#pragma unroll
    for (int m = 4; m < 64; m <<= 1) mx = fmaxf(mx, __shfl_xor(mx, m, 64));
    // pass 2: per-head sum of exp
    float sm = 0.f;
    for (int e = beg + (lane >> 2); e < end; e += 16) {
        const int s = esrc[e];
        float v = als[s * 4 + h1] + aldn1;
        v = (v > 0.f) ? v : SLOPE * v;
        sm += __expf(v - mx);
    }
#pragma unroll
    for (int m = 4; m < 64; m <<= 1) sm += __shfl_xor(sm, m, 64);
    // redistribute to channel layout: lane handles channels 4*lane..+3, head = lane>>4
    const int head = lane >> 4;
    const float mh = __shfl(mx, head, 64);   // lane h holds head h's reduced value
    const float dh = __shfl(sm, head, 64);
    const float aldn = ald[n * 4 + head];
    const float invd = 1.f / (dh + 1e-16f);
    float4 acc = {0.f, 0.f, 0.f, 0.f};
    for (int e = beg; e < end; ++e) {
        const int s = esrc[e];
        float v = als[s * 4 + head] + aldn;
        v = (v > 0.f) ? v : SLOPE * v;
        const float al = __expf(v - mh) * invd;
        const float4 hv = *(const float4*)(hin + (size_t)s * 256 + lane * 4);
        acc.x += al * hv.x; acc.y += al * hv.y; acc.z += al * hv.z; acc.w += al * hv.w;
    }
    const int c = lane * 4;
    float y[4] = {acc.x, acc.y, acc.z, acc.w};
#pragma unroll
    for (int i = 0; i < 4; ++i) {
        float t = y[i] + bias[c + i];
        t = (t - mean[c + i]) * rsqrtf(var[c + i] + EPS_BN) * gamma[c + i] + beta[c + i];
        y[i] = fmaxf(t, 0.f);
    }
    float4 o; o.x = y[0]; o.y = y[1]; o.z = y[2]; o.w = y[3];
    *(float4*)(outp + (size_t)n * 256 + c) = o;
}

// ---------------- fused GAT aggregate, 1 head, 64 ch, +bias +ReLU ----------------
__global__ __launch_bounds__(256) void k_agg1(const float* __restrict__ hin,
                                              const float* __restrict__ als,
                                              const float* __restrict__ ald,
                                              const int* __restrict__ indptr,
                                              const int* __restrict__ esrc,
                                              const float* __restrict__ bias,
                                              float* __restrict__ outp) {
    const int n = blockIdx.x * 4 + (threadIdx.x >> 6);
    const int lane = threadIdx.x & 63;
    const int beg = indptr[n], end = indptr[n + 1];
    const float aldn = ald[n];
    float mx = -3.0e38f;
    for (int e = beg + lane; e < end; e += 64) {
        const int s = esrc[e];
        float v = als[s] + aldn;
        v = (v > 0.f) ? v : SLOPE * v;
        mx = fmaxf(mx, v);
    }
#pragma unroll
    for (int m = 1; m < 64; m <<= 1) mx = fmaxf(mx, __shfl_xor(mx, m, 64));
    float sm = 0.f;
    for (int e = beg + lane; e < end; e += 64) {
        const int s = esrc[e];
        float v = als[s] + aldn;
        v = (v > 0.f) ? v : SLOPE * v;
        sm += __expf(v - mx);
    }
#pragma unroll
    for (int m = 1; m < 64; m <<= 1) sm += __shfl_xor(sm, m, 64);
    const float invd = 1.f / (sm + 1e-16f);
    float acc = 0.f;
    for (int e = beg; e < end; ++e) {
        const int s = esrc[e];
        float v = als[s] + aldn;
        v = (v > 0.f) ? v : SLOPE * v;
        const float al = __expf(v - mx) * invd;
        acc += al * hin[(size_t)s * 64 + lane];
    }
    outp[(size_t)n * 64 + lane] = fmaxf(acc + bias[lane], 0.f);
}

// ---------------- graph ranges from sorted batch ----------------
__global__ void k_gstart(const int* __restrict__ batch, int* __restrict__ gstart) {
    int i = blockIdx.x * 256 + threadIdx.x;
    if (i >= N_NODES) return;
    int b = batch[i];
    if (i == 0) {
        for (int g = 0; g <= b; ++g) gstart[g] = 0;
    } else {
        int p = batch[i - 1];
        for (int g = p + 1; g <= b; ++g) gstart[g] = i;
    }
    if (i == N_NODES - 1) {
        for (int g = b + 1; g <= N_GRAPHS; ++g) gstart[g] = N_NODES;
    }
}

__global__ void k_pool(const float* __restrict__ out3, const int* __restrict__ gstart,
                       float* __restrict__ pooled) {
    const int g = blockIdx.x;
    const int lane = threadIdx.x;  // 64
    const int s = gstart[g], e = gstart[g + 1];
    float acc = 0.f;
    for (int i = s; i < e; ++i) acc += out3[(size_t)i * 64 + lane];
    int cntn = e - s;
    pooled[g * 64 + lane] = acc / (float)max(cntn, 1);
}

__global__ void k_mlp(const float* __restrict__ pooled,
                      const float* __restrict__ w1, const float* __restrict__ b1,
                      const float* __restrict__ w2, const float* __restrict__ b2,
                      float* __restrict__ outp) {
    const int g = blockIdx.x;
    const int t = threadIdx.x;  // 32
    __shared__ float hid[32];
    float acc = b1[t];
    for (int c = 0; c < 64; ++c) acc += pooled[g * 64 + c] * w1[c * 32 + t];
    hid[t] = fmaxf(acc, 0.f);
    __syncthreads();
    if (t < N_CLASSES) {
        float o = b2[t];
        for (int k = 0; k < 32; ++k) o += hid[k] * w2[k * 5 + t];
        outp[g * 5 + t] = o;   // d_out is float32 (reference output dtype)
    }
}

extern "C" void kernel_launch(void* const* d_in, const int* in_sizes, int n_in,
                              void* d_out, int out_size, void* d_ws, size_t ws_size,
                              hipStream_t stream) {
    const float* x        = (const float*)d_in[0];
    const int* edge_index = (const int*)d_in[1];
    const int* batch      = (const int*)d_in[2];
    const float* W1  = (const float*)d_in[3];
    const float* a1s = (const float*)d_in[4];
    const float* a1d = (const float*)d_in[5];
    const float* b1  = (const float*)d_in[6];
    const float* g1  = (const float*)d_in[7];
    const float* be1 = (const float*)d_in[8];
    const float* mu1 = (const float*)d_in[9];
    const float* va1 = (const float*)d_in[10];
    const float* W2  = (const float*)d_in[11];
    const float* a2s = (const float*)d_in[12];
    const float* a2d = (const float*)d_in[13];
    const float* b2  = (const float*)d_in[14];
    const float* g2  = (const float*)d_in[15];
    const float* be2 = (const float*)d_in[16];
    const float* mu2 = (const float*)d_in[17];
    const float* va2 = (const float*)d_in[18];
    const float* W3  = (const float*)d_in[19];
    const float* a3s = (const float*)d_in[20];
    const float* a3d = (const float*)d_in[21];
    const float* b3  = (const float*)d_in[22];
    const float* l1w = (const float*)d_in[23];
    const float* l1b = (const float*)d_in[24];
    const float* l2w = (const float*)d_in[25];
    const float* l2b = (const float*)d_in[26];
    float* out = (float*)d_out;

    char* w = (char*)d_ws;
    size_t off = 0;
    auto alloc = [&](size_t bytes) -> void* {
        void* p = w + off;
        off += (bytes + 255) & ~(size_t)255;
        return p;
    };
    float* bufA   = (float*)alloc((size_t)N_NODES * 256 * 4);
    float* bufB   = (float*)alloc((size_t)N_NODES * 256 * 4);
    float* als    = (float*)alloc((size_t)N_NODES * 4 * 4);
    float* ald    = (float*)alloc((size_t)N_NODES * 4 * 4);
    int* cnt      = (int*)alloc((size_t)N_NODES * 4);
    int* wptr     = (int*)alloc((size_t)N_NODES * 4);
    int* indptr   = (int*)alloc((size_t)(N_NODES + 1) * 4);
    int* esrc     = (int*)alloc((size_t)E_TOT * 4);
    int* gstart   = (int*)alloc((size_t)(N_GRAPHS + 1) * 4);
    float* pooled = (float*)alloc((size_t)N_GRAPHS * 64 * 4);

    // CSR by dst (graph is identical for all 3 layers)
    k_zero<<<(N_NODES + 255) / 256, 256, 0, stream>>>(cnt, N_NODES);
    k_count<<<(E_TOT + 255) / 256, 256, 0, stream>>>(edge_index, cnt);
    k_scan<<<1, 1024, 0, stream>>>(cnt, indptr, wptr);
    k_scatter<<<(E_TOT + 255) / 256, 256, 0, stream>>>(edge_index, wptr, esrc);

    const int MB = (N_NODES + 63) / 64;  // 313

    // layer 1
    k_gemm<<<dim3(MB, 4), 256, 0, stream>>>(x, W1, bufA, N_NODES, 512, 256);
    k_al<4><<<N_NODES / 4, 256, 0, stream>>>(bufA, a1s, a1d, als, ald);
    k_agg4<<<N_NODES / 4, 256, 0, stream>>>(bufA, als, ald, indptr, esrc, b1, g1, be1, mu1, va1, bufB);
    // layer 2
    k_gemm<<<dim3(MB, 4), 256, 0, stream>>>(bufB, W2, bufA, N_NODES, 256, 256);
    k_al<4><<<N_NODES / 4, 256, 0, stream>>>(bufA, a2s, a2d, als, ald);
    k_agg4<<<N_NODES / 4, 256, 0, stream>>>(bufA, als, ald, indptr, esrc, b2, g2, be2, mu2, va2, bufB);
    // layer 3
    k_gemm<<<dim3(MB, 1), 256, 0, stream>>>(bufB, W3, bufA, N_NODES, 256, 64);
    k_al<1><<<N_NODES / 4, 256, 0, stream>>>(bufA, a3s, a3d, als, ald);
    k_agg1<<<N_NODES / 4, 256, 0, stream>>>(bufA, als, ald, indptr, esrc, b3, bufB);
    // readout
    k_gstart<<<(N_NODES + 255) / 256, 256, 0, stream>>>(batch, gstart);
    k_pool<<<N_GRAPHS, 64, 0, stream>>>(bufB, gstart, pooled);
    k_mlp<<<N_GRAPHS, 32, 0, stream>>>(pooled, l1w, l1b, l2w, l2b, out);
}